// Round 1
// baseline (637.938 us; speedup 1.0000x reference)
//
#include <hip/hip_runtime.h>
#include <hip/hip_bf16.h>

typedef _Float16 f16;
typedef _Float16 f16x4 __attribute__((ext_vector_type(4)));
typedef _Float16 f16x8 __attribute__((ext_vector_type(8)));
typedef float f32x4 __attribute__((ext_vector_type(4)));

#define DEV static __device__ __forceinline__

DEV void gld_lds16(const void* g, void* l) {
  __builtin_amdgcn_global_load_lds(
      (const __attribute__((address_space(1))) void*)g,
      (__attribute__((address_space(3))) void*)l, 16, 0, 0);
}

DEV float fast_tanh(float x) {
  float e = __expf(2.0f * x);
  return 1.0f - 2.0f / (e + 1.0f);  // large +x: e=inf -> 1; large -x: e=0 -> -1
}

// ---------------- x (f32) -> xh (f16) ----------------
__global__ __launch_bounds__(256) void k_cvt_x(const float* __restrict__ x,
                                               f16* __restrict__ xh, long n) {
  long i0 = ((long)blockIdx.x * 256 + threadIdx.x) * 4;
  long stride = (long)gridDim.x * 1024;
  for (long i = i0; i < n; i += stride) {
    const float4 v = *(const float4*)(x + i);
    f16x4 h;
    h.x = (f16)v.x; h.y = (f16)v.y; h.z = (f16)v.z; h.w = (f16)v.w;
    *(f16x4*)(xh + i) = h;
  }
}

// ---------------- W [E][K][N] f32  ->  Wt [E][N][K] f16, optional col-scale 1/std[k]
__global__ __launch_bounds__(256) void k_transpose(const float* __restrict__ in,
                                                   f16* __restrict__ out,
                                                   const float* __restrict__ stdv,
                                                   int K_, int N_) {
  __shared__ float tile[32][33];
  const int e = blockIdx.z;
  const float* ine = in + (long)e * K_ * N_;
  f16* oute = out + (long)e * K_ * N_;
  const int n0 = blockIdx.x * 32, k0 = blockIdx.y * 32;
  const int tx = threadIdx.x, ty = threadIdx.y;
#pragma unroll
  for (int j = 0; j < 4; j++)
    tile[ty + j * 8][tx] = ine[(long)(k0 + ty + j * 8) * N_ + n0 + tx];
  __syncthreads();
  const float rs = stdv ? 1.0f / stdv[(long)e * K_ + k0 + tx] : 1.0f;
#pragma unroll
  for (int j = 0; j < 4; j++)
    oute[(long)(n0 + ty + j * 8) * K_ + k0 + tx] = (f16)(tile[tx][ty + j * 8] * rs);
}

// ---------------- corrected bias: outb[e][h] = b[e][h] - sum_s (mean/std)[e][s]*W[e][s][h]
__global__ __launch_bounds__(256) void k_bias_corr(const float* __restrict__ W,
                                                   const float* __restrict__ b,
                                                   const float* __restrict__ mean,
                                                   const float* __restrict__ stdv,
                                                   float* __restrict__ outb,
                                                   int S_, int H_) {
  const int e = blockIdx.y;
  const float* We = W + (long)e * S_ * H_;
  const float* me = mean + (long)e * S_;
  const float* se = stdv + (long)e * S_;
  const int h = blockIdx.x * 256 + threadIdx.x;
  float acc = 0.0f;
  for (int s = 0; s < S_; s++) acc += (me[s] / se[s]) * We[(long)s * H_ + h];
  outb[(long)e * H_ + h] = b[(long)e * H_ + h] - acc;
}

// ---------------- main GEMM: C = tanh(A @ Bt^T + bias), all f16 in/out, f32 accum
// A [M,K] row-major f16, Bt [N,K] f16, bias [N] f32, C [M,N] f16
// grid (N/128, M/128), 256 threads, m97 structure
__global__ __launch_bounds__(256) void k_gemm_tanh(const f16* __restrict__ A,
                                                   const f16* __restrict__ Bt,
                                                   const float* __restrict__ bias,
                                                   f16* __restrict__ C,
                                                   int M, int N, int K) {
  __shared__ __align__(16) f16 As[128 * 64];
  __shared__ __align__(16) f16 Bs[128 * 64];
  const int tid = threadIdx.x;
  const int wave = tid >> 6, lane = tid & 63;
  const int m0 = blockIdx.y * 128, n0 = blockIdx.x * 128;
  const int wr = wave >> 1, wc = wave & 1;
  f32x4 acc[4][4] = {};
  const f16* Ag = A + (long)(m0 + tid / 8) * K + (tid % 8) * 8;
  const f16* Bg = Bt + (long)(n0 + tid / 8) * K + (tid % 8) * 8;
  f16* AsW = As + wave * 512;
  f16* BsW = Bs + wave * 512;
  for (int kt = 0; kt < K; kt += 64) {
    __syncthreads();
#pragma unroll
    for (int i = 0; i < 4; i++) {
      gld_lds16(Ag + (long)i * 32 * K + kt, AsW + i * 2048);
      gld_lds16(Bg + (long)i * 32 * K + kt, BsW + i * 2048);
    }
    __syncthreads();
#pragma unroll
    for (int kk = 0; kk < 2; kk++) {
      f16x8 af[4], bfr[4];
#pragma unroll
      for (int mi = 0; mi < 4; mi++)
        af[mi] = *(const f16x8*)&As[(wr * 64 + mi * 16 + (lane & 15)) * 64 + kk * 32 + (lane >> 4) * 8];
#pragma unroll
      for (int ni = 0; ni < 4; ni++)
        bfr[ni] = *(const f16x8*)&Bs[(wc * 64 + ni * 16 + (lane & 15)) * 64 + kk * 32 + (lane >> 4) * 8];
#pragma unroll
      for (int mi = 0; mi < 4; mi++)
#pragma unroll
        for (int ni = 0; ni < 4; ni++)
          acc[mi][ni] = __builtin_amdgcn_mfma_f32_16x16x32_f16(af[mi], bfr[ni], acc[mi][ni], 0, 0, 0);
    }
  }
  const int r0 = (lane >> 4) * 4, cb = lane & 15;
#pragma unroll
  for (int ni = 0; ni < 4; ni++) {
    const int col = n0 + wc * 64 + ni * 16 + cb;
    const float bc = bias[col];
#pragma unroll
    for (int mi = 0; mi < 4; mi++) {
      const int row = m0 + wr * 64 + mi * 16 + r0;
#pragma unroll
      for (int r = 0; r < 4; r++)
        C[(long)(row + r) * N + col] = (f16)fast_tanh(acc[mi][ni][r] + bc);
    }
  }
}

// ---------------- gating head: logits = h1 @ gWa + gba; softmax over 4 -> gw [B,4] f32
__global__ __launch_bounds__(256) void k_gating_head(const f16* __restrict__ h1,
                                                     const float* __restrict__ gWa,
                                                     const float* __restrict__ gba,
                                                     float* __restrict__ gw, int B_) {
  const int b = blockIdx.x * 4 + (threadIdx.x >> 6);
  const int lane = threadIdx.x & 63;
  const f16x4 hv = *(const f16x4*)&h1[(long)b * 256 + lane * 4];
  float s0 = 0, s1 = 0, s2 = 0, s3 = 0;
#pragma unroll
  for (int j = 0; j < 4; j++) {
    const float hh = (float)hv[j];
    const float4 wr4 = *(const float4*)&gWa[(lane * 4 + j) * 4];
    s0 += hh * wr4.x; s1 += hh * wr4.y; s2 += hh * wr4.z; s3 += hh * wr4.w;
  }
#pragma unroll
  for (int off = 32; off >= 1; off >>= 1) {
    s0 += __shfl_xor(s0, off);
    s1 += __shfl_xor(s1, off);
    s2 += __shfl_xor(s2, off);
    s3 += __shfl_xor(s3, off);
  }
  const float l0 = s0 + gba[0], l1 = s1 + gba[1], l2 = s2 + gba[2], l3 = s3 + gba[3];
  float mx = fmaxf(fmaxf(l0, l1), fmaxf(l2, l3));
  const float e0 = __expf(l0 - mx), e1 = __expf(l1 - mx), e2 = __expf(l2 - mx), e3 = __expf(l3 - mx);
  const float inv = 1.0f / (e0 + e1 + e2 + e3);
  if (lane == 0) {
    float4 o; o.x = e0 * inv; o.y = e1 * inv; o.z = e2 * inv; o.w = e3 * inv;
    *(float4*)&gw[(long)b * 4] = o;
  }
}

// ---------------- expert head: out[b,a] (+)= gw[b,e] * ((he1 @ Wt^T)[b,a] + eba[a]) * scale[a]
// he1 [M,K] f16, Wt [64,K] f16. grid M/64, 256 threads (4 waves x 16 rows).
__global__ __launch_bounds__(256) void k_head(const f16* __restrict__ he1,
                                              const f16* __restrict__ Wt,
                                              const float* __restrict__ eba_e,
                                              const float* __restrict__ scale,
                                              const float* __restrict__ gw,
                                              float* __restrict__ out,
                                              int e, int first, int K) {
  __shared__ __align__(16) f16 As[64 * 64];
  __shared__ __align__(16) f16 Bs[64 * 64];
  const int tid = threadIdx.x;
  const int wave = tid >> 6, lane = tid & 63;
  const long m0 = (long)blockIdx.x * 64;
  f32x4 acc[4] = {};
  const f16* Ag = he1 + (m0 + tid / 8) * K + (tid % 8) * 8;
  const f16* Bg = Wt + (long)(tid / 8) * K + (tid % 8) * 8;
  f16* AsW = As + wave * 512;
  f16* BsW = Bs + wave * 512;
  for (int kt = 0; kt < K; kt += 64) {
    __syncthreads();
#pragma unroll
    for (int i = 0; i < 2; i++) {
      gld_lds16(Ag + (long)i * 32 * K + kt, AsW + i * 2048);
      gld_lds16(Bg + (long)i * 32 * K + kt, BsW + i * 2048);
    }
    __syncthreads();
#pragma unroll
    for (int kk = 0; kk < 2; kk++) {
      const f16x8 a = *(const f16x8*)&As[(wave * 16 + (lane & 15)) * 64 + kk * 32 + (lane >> 4) * 8];
#pragma unroll
      for (int ni = 0; ni < 4; ni++) {
        const f16x8 bq = *(const f16x8*)&Bs[(ni * 16 + (lane & 15)) * 64 + kk * 32 + (lane >> 4) * 8];
        acc[ni] = __builtin_amdgcn_mfma_f32_16x16x32_f16(a, bq, acc[ni], 0, 0, 0);
      }
    }
  }
  const int r0 = (lane >> 4) * 4, cb = lane & 15;
#pragma unroll
  for (int ni = 0; ni < 4; ni++) {
    const int col = ni * 16 + cb;
    const float sb = scale[col], bb = eba_e[col];
    const long row0 = m0 + wave * 16 + r0;
#pragma unroll
    for (int r = 0; r < 4; r++) {
      const long row = row0 + r;
      const float wgt = gw[row * 4 + e];
      float val = (acc[ni][r] + bb) * sb * wgt;
      float* p = out + row * 64 + col;
      if (!first) val += *p;
      *p = val;
    }
  }
}

// ---------------- launch ----------------
extern "C" void kernel_launch(void* const* d_in, const int* in_sizes, int n_in,
                              void* d_out, int out_size, void* d_ws, size_t ws_size,
                              hipStream_t stream) {
  constexpr int Bn = 16384, S = 512, H0G = 512, H1G = 256, H0E = 1024, H1E = 512, A = 64, E = 4;
  const float* x      = (const float*)d_in[0];
  const float* g_mean = (const float*)d_in[1];
  const float* g_std  = (const float*)d_in[2];
  const float* gW0    = (const float*)d_in[3];
  const float* gb0    = (const float*)d_in[4];
  const float* gW1    = (const float*)d_in[5];
  const float* gb1    = (const float*)d_in[6];
  const float* gWa    = (const float*)d_in[7];
  const float* gba    = (const float*)d_in[8];
  const float* e_mean = (const float*)d_in[9];
  const float* e_std  = (const float*)d_in[10];
  const float* eW0    = (const float*)d_in[11];
  const float* eb0    = (const float*)d_in[12];
  const float* eW1    = (const float*)d_in[13];
  const float* eb1    = (const float*)d_in[14];
  const float* eWa    = (const float*)d_in[15];
  const float* eba    = (const float*)d_in[16];
  const float* scale  = (const float*)d_in[17];
  float* out = (float*)d_out;

  char* p = (char*)d_ws;
  auto alloc = [&](size_t bytes) { char* q = p; p += (bytes + 255) & ~(size_t)255; return q; };
  f16* xh    = (f16*)alloc((size_t)Bn * S * 2);        // 16 MB
  f16* h0g   = (f16*)alloc((size_t)Bn * H0G * 2);      // 16 MB (reused as he1)
  f16* h1g   = (f16*)alloc((size_t)Bn * H1G * 2);      // 8 MB
  float* gw  = (float*)alloc((size_t)Bn * E * 4);      // 256 KB
  f16* he0   = (f16*)alloc((size_t)Bn * H0E * 2);      // 32 MB
  f16* gW0t  = (f16*)alloc((size_t)S * H0G * 2);
  f16* gW1t  = (f16*)alloc((size_t)H0G * H1G * 2);
  f16* eW0t  = (f16*)alloc((size_t)E * S * H0E * 2);
  f16* eW1t  = (f16*)alloc((size_t)E * H0E * H1E * 2);
  f16* eWat  = (f16*)alloc((size_t)E * H1E * A * 2);
  float* gb0c = (float*)alloc((size_t)H0G * 4);
  float* eb0c = (float*)alloc((size_t)E * H0E * 4);
  f16* he1 = h0g;  // h0g dead after gating layer 1

  // prep: casts / transposes / bias folds
  k_cvt_x<<<2048, 256, 0, stream>>>(x, xh, (long)Bn * S);
  k_transpose<<<dim3(H0G / 32, S / 32, 1), dim3(32, 8), 0, stream>>>(gW0, gW0t, g_std, S, H0G);
  k_transpose<<<dim3(H1G / 32, H0G / 32, 1), dim3(32, 8), 0, stream>>>(gW1, gW1t, nullptr, H0G, H1G);
  k_transpose<<<dim3(H0E / 32, S / 32, E), dim3(32, 8), 0, stream>>>(eW0, eW0t, e_std, S, H0E);
  k_transpose<<<dim3(H1E / 32, H0E / 32, E), dim3(32, 8), 0, stream>>>(eW1, eW1t, nullptr, H0E, H1E);
  k_transpose<<<dim3(A / 32, H1E / 32, E), dim3(32, 8), 0, stream>>>(eWa, eWat, nullptr, H1E, A);
  k_bias_corr<<<dim3(H0G / 256, 1), 256, 0, stream>>>(gW0, gb0, g_mean, g_std, gb0c, S, H0G);
  k_bias_corr<<<dim3(H0E / 256, E), 256, 0, stream>>>(eW0, eb0, e_mean, e_std, eb0c, S, H0E);

  // gating trunk + softmax head
  k_gemm_tanh<<<dim3(H0G / 128, Bn / 128), 256, 0, stream>>>(xh, gW0t, gb0c, h0g, Bn, H0G, S);
  k_gemm_tanh<<<dim3(H1G / 128, Bn / 128), 256, 0, stream>>>(h0g, gW1t, gb1, h1g, Bn, H1G, H0G);
  k_gating_head<<<Bn / 4, 256, 0, stream>>>(h1g, gWa, gba, gw, Bn);

  // experts, sequential, accumulate into out
  for (int e = 0; e < E; e++) {
    k_gemm_tanh<<<dim3(H0E / 128, Bn / 128), 256, 0, stream>>>(
        xh, eW0t + (size_t)e * S * H0E, eb0c + (size_t)e * H0E, he0, Bn, H0E, S);
    k_gemm_tanh<<<dim3(H1E / 128, Bn / 128), 256, 0, stream>>>(
        he0, eW1t + (size_t)e * H0E * H1E, eb1 + (size_t)e * H1E, he1, Bn, H1E, H0E);
    k_head<<<Bn / 64, 256, 0, stream>>>(
        he1, eWat + (size_t)e * H1E * A, eba + (size_t)e * A, scale, gw, out, e, e == 0, H1E);
  }
}

// Round 2
// 402.332 us; speedup vs baseline: 1.5856x; 1.5856x over previous
//
#include <hip/hip_runtime.h>
#include <hip/hip_bf16.h>

typedef _Float16 f16;
typedef _Float16 f16x4 __attribute__((ext_vector_type(4)));
typedef _Float16 f16x8 __attribute__((ext_vector_type(8)));
typedef float f32x4 __attribute__((ext_vector_type(4)));

#define DEV static __device__ __forceinline__

DEV void gld_lds16(const void* g, void* l) {
  __builtin_amdgcn_global_load_lds(
      (const __attribute__((address_space(1))) void*)g,
      (__attribute__((address_space(3))) void*)l, 16, 0, 0);
}

DEV float fast_tanh(float x) {
  float e = __expf(2.0f * x);
  return 1.0f - 2.0f / (e + 1.0f);  // large +x: e=inf -> 1; large -x: e=0 -> -1
}

// ---------------- x (f32) -> xh (f16) ----------------
__global__ __launch_bounds__(256) void k_cvt_x(const float* __restrict__ x,
                                               f16* __restrict__ xh, long n) {
  long i0 = ((long)blockIdx.x * 256 + threadIdx.x) * 4;
  long stride = (long)gridDim.x * 1024;
  for (long i = i0; i < n; i += stride) {
    const float4 v = *(const float4*)(x + i);
    f16x4 h;
    h.x = (f16)v.x; h.y = (f16)v.y; h.z = (f16)v.z; h.w = (f16)v.w;
    *(f16x4*)(xh + i) = h;
  }
}

// ---------------- W [E][K][N] f32  ->  Wt [E][N][K] f16, optional col-scale 1/std[k]
__global__ __launch_bounds__(256) void k_transpose(const float* __restrict__ in,
                                                   f16* __restrict__ out,
                                                   const float* __restrict__ stdv,
                                                   int K_, int N_) {
  __shared__ float tile[32][33];
  const int e = blockIdx.z;
  const float* ine = in + (long)e * K_ * N_;
  f16* oute = out + (long)e * K_ * N_;
  const int n0 = blockIdx.x * 32, k0 = blockIdx.y * 32;
  const int tx = threadIdx.x, ty = threadIdx.y;
#pragma unroll
  for (int j = 0; j < 4; j++)
    tile[ty + j * 8][tx] = ine[(long)(k0 + ty + j * 8) * N_ + n0 + tx];
  __syncthreads();
  const float rs = stdv ? 1.0f / stdv[(long)e * K_ + k0 + tx] : 1.0f;
#pragma unroll
  for (int j = 0; j < 4; j++)
    oute[(long)(n0 + ty + j * 8) * K_ + k0 + tx] = (f16)(tile[tx][ty + j * 8] * rs);
}

// ---------------- corrected bias: outb[e][h] = b[e][h] - sum_s (mean/std)[e][s]*W[e][s][h]
// block: 64 h-lanes x 16 s-slices, LDS tree reduce; grid (H/64, E)
__global__ __launch_bounds__(1024) void k_bias_corr(const float* __restrict__ W,
                                                    const float* __restrict__ b,
                                                    const float* __restrict__ mean,
                                                    const float* __restrict__ stdv,
                                                    float* __restrict__ outb,
                                                    int S_, int H_) {
  __shared__ float red[16][64];
  const int e = blockIdx.y;
  const float* We = W + (long)e * S_ * H_;
  const float* me = mean + (long)e * S_;
  const float* se = stdv + (long)e * S_;
  const int h = blockIdx.x * 64 + threadIdx.x;
  const int sl = threadIdx.y;
  float acc = 0.0f;
#pragma unroll 4
  for (int s = sl; s < S_; s += 16) acc += (me[s] / se[s]) * We[(long)s * H_ + h];
  red[sl][threadIdx.x] = acc;
  __syncthreads();
  if (sl == 0) {
    float a = 0.0f;
#pragma unroll
    for (int j = 0; j < 16; j++) a += red[j][threadIdx.x];
    outb[(long)e * H_ + h] = b[(long)e * H_ + h] - a;
  }
}

// ---------------- main GEMM: C = tanh(A @ Bt^T + bias), all f16 in/out, f32 accum
// A [M,K] row-major f16, Bt [N,K] f16, bias [N] f32, C [M,N] f16
// grid (N/128, M/128), 256 threads, m97 structure
__global__ __launch_bounds__(256) void k_gemm_tanh(const f16* __restrict__ A,
                                                   const f16* __restrict__ Bt,
                                                   const float* __restrict__ bias,
                                                   f16* __restrict__ C,
                                                   int M, int N, int K) {
  __shared__ __align__(16) f16 As[128 * 64];
  __shared__ __align__(16) f16 Bs[128 * 64];
  const int tid = threadIdx.x;
  const int wave = tid >> 6, lane = tid & 63;
  const int m0 = blockIdx.y * 128, n0 = blockIdx.x * 128;
  const int wr = wave >> 1, wc = wave & 1;
  f32x4 acc[4][4] = {};
  const f16* Ag = A + (long)(m0 + tid / 8) * K + (tid % 8) * 8;
  const f16* Bg = Bt + (long)(n0 + tid / 8) * K + (tid % 8) * 8;
  f16* AsW = As + wave * 512;
  f16* BsW = Bs + wave * 512;
  for (int kt = 0; kt < K; kt += 64) {
    __syncthreads();
#pragma unroll
    for (int i = 0; i < 4; i++) {
      gld_lds16(Ag + (long)i * 32 * K + kt, AsW + i * 2048);
      gld_lds16(Bg + (long)i * 32 * K + kt, BsW + i * 2048);
    }
    __syncthreads();
#pragma unroll
    for (int kk = 0; kk < 2; kk++) {
      f16x8 af[4], bfr[4];
#pragma unroll
      for (int mi = 0; mi < 4; mi++)
        af[mi] = *(const f16x8*)&As[(wr * 64 + mi * 16 + (lane & 15)) * 64 + kk * 32 + (lane >> 4) * 8];
#pragma unroll
      for (int ni = 0; ni < 4; ni++)
        bfr[ni] = *(const f16x8*)&Bs[(wc * 64 + ni * 16 + (lane & 15)) * 64 + kk * 32 + (lane >> 4) * 8];
#pragma unroll
      for (int mi = 0; mi < 4; mi++)
#pragma unroll
        for (int ni = 0; ni < 4; ni++)
          acc[mi][ni] = __builtin_amdgcn_mfma_f32_16x16x32_f16(af[mi], bfr[ni], acc[mi][ni], 0, 0, 0);
    }
  }
  const int r0 = (lane >> 4) * 4, cb = lane & 15;
#pragma unroll
  for (int ni = 0; ni < 4; ni++) {
    const int col = n0 + wc * 64 + ni * 16 + cb;
    const float bc = bias[col];
#pragma unroll
    for (int mi = 0; mi < 4; mi++) {
      const int row = m0 + wr * 64 + mi * 16 + r0;
#pragma unroll
      for (int r = 0; r < 4; r++)
        C[(long)(row + r) * N + col] = (f16)fast_tanh(acc[mi][ni][r] + bc);
    }
  }
}

// ---------------- gating head: logits = h1 @ gWa + gba; softmax over 4 -> gw [B,4] f32
__global__ __launch_bounds__(256) void k_gating_head(const f16* __restrict__ h1,
                                                     const float* __restrict__ gWa,
                                                     const float* __restrict__ gba,
                                                     float* __restrict__ gw, int B_) {
  const int b = blockIdx.x * 4 + (threadIdx.x >> 6);
  const int lane = threadIdx.x & 63;
  const f16x4 hv = *(const f16x4*)&h1[(long)b * 256 + lane * 4];
  float s0 = 0, s1 = 0, s2 = 0, s3 = 0;
#pragma unroll
  for (int j = 0; j < 4; j++) {
    const float hh = (float)hv[j];
    const float4 wr4 = *(const float4*)&gWa[(lane * 4 + j) * 4];
    s0 += hh * wr4.x; s1 += hh * wr4.y; s2 += hh * wr4.z; s3 += hh * wr4.w;
  }
#pragma unroll
  for (int off = 32; off >= 1; off >>= 1) {
    s0 += __shfl_xor(s0, off);
    s1 += __shfl_xor(s1, off);
    s2 += __shfl_xor(s2, off);
    s3 += __shfl_xor(s3, off);
  }
  const float l0 = s0 + gba[0], l1 = s1 + gba[1], l2 = s2 + gba[2], l3 = s3 + gba[3];
  float mx = fmaxf(fmaxf(l0, l1), fmaxf(l2, l3));
  const float e0 = __expf(l0 - mx), e1 = __expf(l1 - mx), e2 = __expf(l2 - mx), e3 = __expf(l3 - mx);
  const float inv = 1.0f / (e0 + e1 + e2 + e3);
  if (lane == 0) {
    float4 o; o.x = e0 * inv; o.y = e1 * inv; o.z = e2 * inv; o.w = e3 * inv;
    *(float4*)&gw[(long)b * 4] = o;
  }
}

// ---------------- expert head: out[b,a] (+)= gw[b,e] * ((he1 @ Wt^T)[b,a] + eba[a]) * scale[a]
// he1 [M,K] f16, Wt [64,K] f16. grid M/64, 256 threads (4 waves x 16 rows).
__global__ __launch_bounds__(256) void k_head(const f16* __restrict__ he1,
                                              const f16* __restrict__ Wt,
                                              const float* __restrict__ eba_e,
                                              const float* __restrict__ scale,
                                              const float* __restrict__ gw,
                                              float* __restrict__ out,
                                              int e, int first, int K) {
  __shared__ __align__(16) f16 As[64 * 64];
  __shared__ __align__(16) f16 Bs[64 * 64];
  const int tid = threadIdx.x;
  const int wave = tid >> 6, lane = tid & 63;
  const long m0 = (long)blockIdx.x * 64;
  f32x4 acc[4] = {};
  const f16* Ag = he1 + (m0 + tid / 8) * K + (tid % 8) * 8;
  const f16* Bg = Wt + (long)(tid / 8) * K + (tid % 8) * 8;
  f16* AsW = As + wave * 512;
  f16* BsW = Bs + wave * 512;
  for (int kt = 0; kt < K; kt += 64) {
    __syncthreads();
#pragma unroll
    for (int i = 0; i < 2; i++) {
      gld_lds16(Ag + (long)i * 32 * K + kt, AsW + i * 2048);
      gld_lds16(Bg + (long)i * 32 * K + kt, BsW + i * 2048);
    }
    __syncthreads();
#pragma unroll
    for (int kk = 0; kk < 2; kk++) {
      const f16x8 a = *(const f16x8*)&As[(wave * 16 + (lane & 15)) * 64 + kk * 32 + (lane >> 4) * 8];
#pragma unroll
      for (int ni = 0; ni < 4; ni++) {
        const f16x8 bq = *(const f16x8*)&Bs[(ni * 16 + (lane & 15)) * 64 + kk * 32 + (lane >> 4) * 8];
        acc[ni] = __builtin_amdgcn_mfma_f32_16x16x32_f16(a, bq, acc[ni], 0, 0, 0);
      }
    }
  }
  const int r0 = (lane >> 4) * 4, cb = lane & 15;
#pragma unroll
  for (int ni = 0; ni < 4; ni++) {
    const int col = ni * 16 + cb;
    const float sb = scale[col], bb = eba_e[col];
    const long row0 = m0 + wave * 16 + r0;
#pragma unroll
    for (int r = 0; r < 4; r++) {
      const long row = row0 + r;
      const float wgt = gw[row * 4 + e];
      float val = (acc[ni][r] + bb) * sb * wgt;
      float* p = out + row * 64 + col;
      if (!first) val += *p;
      *p = val;
    }
  }
}

// ---------------- launch ----------------
extern "C" void kernel_launch(void* const* d_in, const int* in_sizes, int n_in,
                              void* d_out, int out_size, void* d_ws, size_t ws_size,
                              hipStream_t stream) {
  constexpr int Bn = 16384, S = 512, H0G = 512, H1G = 256, H0E = 1024, H1E = 512, A = 64, E = 4;
  const float* x      = (const float*)d_in[0];
  const float* g_mean = (const float*)d_in[1];
  const float* g_std  = (const float*)d_in[2];
  const float* gW0    = (const float*)d_in[3];
  const float* gb0    = (const float*)d_in[4];
  const float* gW1    = (const float*)d_in[5];
  const float* gb1    = (const float*)d_in[6];
  const float* gWa    = (const float*)d_in[7];
  const float* gba    = (const float*)d_in[8];
  const float* e_mean = (const float*)d_in[9];
  const float* e_std  = (const float*)d_in[10];
  const float* eW0    = (const float*)d_in[11];
  const float* eb0    = (const float*)d_in[12];
  const float* eW1    = (const float*)d_in[13];
  const float* eb1    = (const float*)d_in[14];
  const float* eWa    = (const float*)d_in[15];
  const float* eba    = (const float*)d_in[16];
  const float* scale  = (const float*)d_in[17];
  float* out = (float*)d_out;

  char* p = (char*)d_ws;
  auto alloc = [&](size_t bytes) { char* q = p; p += (bytes + 255) & ~(size_t)255; return q; };
  f16* xh    = (f16*)alloc((size_t)Bn * S * 2);        // 16 MB
  f16* h0g   = (f16*)alloc((size_t)Bn * H0G * 2);      // 16 MB (reused as he1)
  f16* h1g   = (f16*)alloc((size_t)Bn * H1G * 2);      // 8 MB
  float* gw  = (float*)alloc((size_t)Bn * E * 4);      // 256 KB
  f16* he0   = (f16*)alloc((size_t)Bn * H0E * 2);      // 32 MB
  f16* gW0t  = (f16*)alloc((size_t)S * H0G * 2);
  f16* gW1t  = (f16*)alloc((size_t)H0G * H1G * 2);
  f16* eW0t  = (f16*)alloc((size_t)E * S * H0E * 2);
  f16* eW1t  = (f16*)alloc((size_t)E * H0E * H1E * 2);
  f16* eWat  = (f16*)alloc((size_t)E * H1E * A * 2);
  float* gb0c = (float*)alloc((size_t)H0G * 4);
  float* eb0c = (float*)alloc((size_t)E * H0E * 4);
  f16* he1 = h0g;  // h0g dead after gating layer 1

  // prep: casts / transposes / bias folds
  k_cvt_x<<<2048, 256, 0, stream>>>(x, xh, (long)Bn * S);
  k_transpose<<<dim3(H0G / 32, S / 32, 1), dim3(32, 8), 0, stream>>>(gW0, gW0t, g_std, S, H0G);
  k_transpose<<<dim3(H1G / 32, H0G / 32, 1), dim3(32, 8), 0, stream>>>(gW1, gW1t, nullptr, H0G, H1G);
  k_transpose<<<dim3(H0E / 32, S / 32, E), dim3(32, 8), 0, stream>>>(eW0, eW0t, e_std, S, H0E);
  k_transpose<<<dim3(H1E / 32, H0E / 32, E), dim3(32, 8), 0, stream>>>(eW1, eW1t, nullptr, H0E, H1E);
  k_transpose<<<dim3(A / 32, H1E / 32, E), dim3(32, 8), 0, stream>>>(eWa, eWat, nullptr, H1E, A);
  k_bias_corr<<<dim3(H0G / 64, 1), dim3(64, 16), 0, stream>>>(gW0, gb0, g_mean, g_std, gb0c, S, H0G);
  k_bias_corr<<<dim3(H0E / 64, E), dim3(64, 16), 0, stream>>>(eW0, eb0, e_mean, e_std, eb0c, S, H0E);

  // gating trunk + softmax head
  k_gemm_tanh<<<dim3(H0G / 128, Bn / 128), 256, 0, stream>>>(xh, gW0t, gb0c, h0g, Bn, H0G, S);
  k_gemm_tanh<<<dim3(H1G / 128, Bn / 128), 256, 0, stream>>>(h0g, gW1t, gb1, h1g, Bn, H1G, H0G);
  k_gating_head<<<Bn / 4, 256, 0, stream>>>(h1g, gWa, gba, gw, Bn);

  // experts, sequential, accumulate into out
  for (int e = 0; e < E; e++) {
    k_gemm_tanh<<<dim3(H0E / 128, Bn / 128), 256, 0, stream>>>(
        xh, eW0t + (size_t)e * S * H0E, eb0c + (size_t)e * H0E, he0, Bn, H0E, S);
    k_gemm_tanh<<<dim3(H1E / 128, Bn / 128), 256, 0, stream>>>(
        he0, eW1t + (size_t)e * H0E * H1E, eb1 + (size_t)e * H1E, he1, Bn, H1E, H0E);
    k_head<<<Bn / 64, 256, 0, stream>>>(
        he1, eWat + (size_t)e * H1E * A, eba + (size_t)e * A, scale, gw, out, e, e == 0, H1E);
  }
}

// Round 3
// 389.426 us; speedup vs baseline: 1.6381x; 1.0331x over previous
//
#include <hip/hip_runtime.h>
#include <hip/hip_bf16.h>

typedef _Float16 f16;
typedef _Float16 f16x4 __attribute__((ext_vector_type(4)));
typedef _Float16 f16x8 __attribute__((ext_vector_type(8)));
typedef float f32x4 __attribute__((ext_vector_type(4)));

#define DEV static __device__ __forceinline__

DEV void gld_lds16(const void* g, void* l) {
  __builtin_amdgcn_global_load_lds(
      (const __attribute__((address_space(1))) void*)g,
      (__attribute__((address_space(3))) void*)l, 16, 0, 0);
}

DEV float fast_tanh(float x) {
  float e = __expf(2.0f * x);
  return 1.0f - 2.0f / (e + 1.0f);
}

DEV int xcd_swizzle(int raw, int nwg) {
  // bijective when nwg % 8 == 0 (all our grids); identity otherwise
  return ((nwg & 7) == 0) ? ((raw & 7) * (nwg >> 3) + (raw >> 3)) : raw;
}

// ---------------- x (f32) -> xh (f16) ----------------
__global__ __launch_bounds__(256) void k_cvt_x(const float* __restrict__ x,
                                               f16* __restrict__ xh, long n) {
  long i0 = ((long)blockIdx.x * 256 + threadIdx.x) * 4;
  long stride = (long)gridDim.x * 1024;
  for (long i = i0; i < n; i += stride) {
    const float4 v = *(const float4*)(x + i);
    f16x4 h;
    h.x = (f16)v.x; h.y = (f16)v.y; h.z = (f16)v.z; h.w = (f16)v.w;
    *(f16x4*)(xh + i) = h;
  }
}

// ---------------- W [E][K][N] f32 -> Wt [E][N][K] f16, optional col-scale 1/std[k]
__global__ __launch_bounds__(256) void k_transpose(const float* __restrict__ in,
                                                   f16* __restrict__ out,
                                                   const float* __restrict__ stdv,
                                                   int K_, int N_) {
  __shared__ float tile[32][33];
  const int e = blockIdx.z;
  const float* ine = in + (long)e * K_ * N_;
  f16* oute = out + (long)e * K_ * N_;
  const int n0 = blockIdx.x * 32, k0 = blockIdx.y * 32;
  const int tx = threadIdx.x, ty = threadIdx.y;
#pragma unroll
  for (int j = 0; j < 4; j++)
    tile[ty + j * 8][tx] = ine[(long)(k0 + ty + j * 8) * N_ + n0 + tx];
  __syncthreads();
  const float rs = stdv ? 1.0f / stdv[(long)e * K_ + k0 + tx] : 1.0f;
#pragma unroll
  for (int j = 0; j < 4; j++)
    oute[(long)(n0 + ty + j * 8) * K_ + k0 + tx] = (f16)(tile[tx][ty + j * 8] * rs);
}

// ---------------- corrected bias: outb[e][h] = b[e][h] - sum_s (mean/std)[e][s]*W[e][s][h]
__global__ __launch_bounds__(1024) void k_bias_corr(const float* __restrict__ W,
                                                    const float* __restrict__ b,
                                                    const float* __restrict__ mean,
                                                    const float* __restrict__ stdv,
                                                    float* __restrict__ outb,
                                                    int S_, int H_) {
  __shared__ float red[16][64];
  const int e = blockIdx.y;
  const float* We = W + (long)e * S_ * H_;
  const float* me = mean + (long)e * S_;
  const float* se = stdv + (long)e * S_;
  const int h = blockIdx.x * 64 + threadIdx.x;
  const int sl = threadIdx.y;
  float acc = 0.0f;
#pragma unroll 4
  for (int s = sl; s < S_; s += 16) acc += (me[s] / se[s]) * We[(long)s * H_ + h];
  red[sl][threadIdx.x] = acc;
  __syncthreads();
  if (sl == 0) {
    float a = 0.0f;
#pragma unroll
    for (int j = 0; j < 16; j++) a += red[j][threadIdx.x];
    outb[(long)e * H_ + h] = b[(long)e * H_ + h] - a;
  }
}

// ---------------- main GEMM: C = tanh(A @ Bt^T + bias), dbuf + single end-drain per iter
// C layout: col c -> C[((c>>cshift)*M + row)*(1<<cshift) + (c & mask)]  (expert-split write)
__global__ __launch_bounds__(256) void k_gemm_tanh(
    const f16* __restrict__ A, const f16* __restrict__ Bt,
    const float* __restrict__ bias, f16* __restrict__ C,
    int M, int N, int K, int cshift,
    long sA, long sB, long sBias, long sC) {
  A += (long)blockIdx.z * sA; Bt += (long)blockIdx.z * sB;
  bias += (long)blockIdx.z * sBias; C += (long)blockIdx.z * sC;
  __shared__ __align__(16) f16 As[2][128 * 64];
  __shared__ __align__(16) f16 Bs[2][128 * 64];
  const int tid = threadIdx.x, wave = tid >> 6, lane = tid & 63;
  const int nwg = gridDim.x * gridDim.y;
  const int logical = xcd_swizzle(blockIdx.y * gridDim.x + blockIdx.x, nwg);
  const int bx = logical % gridDim.x, by = logical / gridDim.x;
  const int m0 = by * 128, n0 = bx * 128;
  const int wr = wave >> 1, wc = wave & 1;
  f32x4 acc[4][4] = {};
  const f16* Ag = A + (long)(m0 + tid / 8) * K + (tid % 8) * 8;
  const f16* Bg = Bt + (long)(n0 + tid / 8) * K + (tid % 8) * 8;
  const int wo = wave * 512;

  // prologue: stage tile 0 into buf 0
#pragma unroll
  for (int i = 0; i < 4; i++) {
    gld_lds16(Ag + (long)i * 32 * K, &As[0][wo + i * 2048]);
    gld_lds16(Bg + (long)i * 32 * K, &Bs[0][wo + i * 2048]);
  }
  __syncthreads();

  const int nt = K >> 6;
  int cur = 0;
  for (int t = 0; t < nt; ++t) {
    if (t + 1 < nt) {
      const long kt = (long)(t + 1) << 6;
#pragma unroll
      for (int i = 0; i < 4; i++) {
        gld_lds16(Ag + (long)i * 32 * K + kt, &As[cur ^ 1][wo + i * 2048]);
        gld_lds16(Bg + (long)i * 32 * K + kt, &Bs[cur ^ 1][wo + i * 2048]);
      }
    }
#pragma unroll
    for (int kk = 0; kk < 2; kk++) {
      f16x8 af[4], bfr[4];
#pragma unroll
      for (int mi = 0; mi < 4; mi++)
        af[mi] = *(const f16x8*)&As[cur][(wr * 64 + mi * 16 + (lane & 15)) * 64 + kk * 32 + (lane >> 4) * 8];
#pragma unroll
      for (int ni = 0; ni < 4; ni++)
        bfr[ni] = *(const f16x8*)&Bs[cur][(wc * 64 + ni * 16 + (lane & 15)) * 64 + kk * 32 + (lane >> 4) * 8];
#pragma unroll
      for (int mi = 0; mi < 4; mi++)
#pragma unroll
        for (int ni = 0; ni < 4; ni++)
          acc[mi][ni] = __builtin_amdgcn_mfma_f32_16x16x32_f16(af[mi], bfr[ni], acc[mi][ni], 0, 0, 0);
    }
    __syncthreads();  // drains vmcnt(0): next buffer staged; WAR-protects buf we stage next iter
    cur ^= 1;
  }

  const int r0 = (lane >> 4) * 4, cb = lane & 15;
  const int cmask = (1 << cshift) - 1;
#pragma unroll
  for (int ni = 0; ni < 4; ni++) {
    const int col = n0 + wc * 64 + ni * 16 + cb;
    const float bc = bias[col];
    const long cbase = (((long)(col >> cshift) * M) << cshift) | (col & cmask);
#pragma unroll
    for (int mi = 0; mi < 4; mi++) {
      const int row = m0 + wr * 64 + mi * 16 + r0;
#pragma unroll
      for (int r = 0; r < 4; r++)
        C[cbase + ((long)(row + r) << cshift)] = (f16)fast_tanh(acc[mi][ni][r] + bc);
    }
  }
}

// ---------------- gating head: logits = h1 @ gWa + gba; softmax over 4 -> gw [B,4] f32
__global__ __launch_bounds__(256) void k_gating_head(const f16* __restrict__ h1,
                                                     const float* __restrict__ gWa,
                                                     const float* __restrict__ gba,
                                                     float* __restrict__ gw, int B_) {
  const int b = blockIdx.x * 4 + (threadIdx.x >> 6);
  const int lane = threadIdx.x & 63;
  const f16x4 hv = *(const f16x4*)&h1[(long)b * 256 + lane * 4];
  float s0 = 0, s1 = 0, s2 = 0, s3 = 0;
#pragma unroll
  for (int j = 0; j < 4; j++) {
    const float hh = (float)hv[j];
    const float4 wr4 = *(const float4*)&gWa[(lane * 4 + j) * 4];
    s0 += hh * wr4.x; s1 += hh * wr4.y; s2 += hh * wr4.z; s3 += hh * wr4.w;
  }
#pragma unroll
  for (int off = 32; off >= 1; off >>= 1) {
    s0 += __shfl_xor(s0, off);
    s1 += __shfl_xor(s1, off);
    s2 += __shfl_xor(s2, off);
    s3 += __shfl_xor(s3, off);
  }
  const float l0 = s0 + gba[0], l1 = s1 + gba[1], l2 = s2 + gba[2], l3 = s3 + gba[3];
  float mx = fmaxf(fmaxf(l0, l1), fmaxf(l2, l3));
  const float e0 = __expf(l0 - mx), e1 = __expf(l1 - mx), e2 = __expf(l2 - mx), e3 = __expf(l3 - mx);
  const float inv = 1.0f / (e0 + e1 + e2 + e3);
  if (lane == 0) {
    float4 o; o.x = e0 * inv; o.y = e1 * inv; o.z = e2 * inv; o.w = e3 * inv;
    *(float4*)&gw[(long)b * 4] = o;
  }
}

// ---------------- expert head: a_all[e][b][a] = gw[b,e] * ((he1 @ Wt^T)[b,a] + eba[a]) * scale[a]
__global__ __launch_bounds__(256) void k_head(const f16* __restrict__ he1,
                                              const f16* __restrict__ Wt,
                                              const float* __restrict__ ebae,
                                              const float* __restrict__ scale,
                                              const float* __restrict__ gw,
                                              float* __restrict__ outa,
                                              int e0, int K,
                                              long sA, long sB, long sBias, long sC) {
  const int z = blockIdx.z;
  he1 += (long)z * sA; Wt += (long)z * sB; ebae += (long)z * sBias; outa += (long)z * sC;
  const int e = e0 + z;
  __shared__ __align__(16) f16 As[2][64 * 64];
  __shared__ __align__(16) f16 Bs[2][64 * 64];
  const int tid = threadIdx.x, wave = tid >> 6, lane = tid & 63;
  const int bid = xcd_swizzle(blockIdx.x, gridDim.x);
  const long m0 = (long)bid * 64;
  f32x4 acc[4] = {};
  const f16* Ag = he1 + (m0 + tid / 8) * K + (tid % 8) * 8;
  const f16* Bg = Wt + (long)(tid / 8) * K + (tid % 8) * 8;
  const int wo = wave * 512;
#pragma unroll
  for (int i = 0; i < 2; i++) {
    gld_lds16(Ag + (long)i * 32 * K, &As[0][wo + i * 2048]);
    gld_lds16(Bg + (long)i * 32 * K, &Bs[0][wo + i * 2048]);
  }
  __syncthreads();
  const int nt = K >> 6;
  int cur = 0;
  for (int t = 0; t < nt; ++t) {
    if (t + 1 < nt) {
      const long kt = (long)(t + 1) << 6;
#pragma unroll
      for (int i = 0; i < 2; i++) {
        gld_lds16(Ag + (long)i * 32 * K + kt, &As[cur ^ 1][wo + i * 2048]);
        gld_lds16(Bg + (long)i * 32 * K + kt, &Bs[cur ^ 1][wo + i * 2048]);
      }
    }
#pragma unroll
    for (int kk = 0; kk < 2; kk++) {
      const f16x8 a = *(const f16x8*)&As[cur][(wave * 16 + (lane & 15)) * 64 + kk * 32 + (lane >> 4) * 8];
#pragma unroll
      for (int ni = 0; ni < 4; ni++) {
        const f16x8 bq = *(const f16x8*)&Bs[cur][(ni * 16 + (lane & 15)) * 64 + kk * 32 + (lane >> 4) * 8];
        acc[ni] = __builtin_amdgcn_mfma_f32_16x16x32_f16(a, bq, acc[ni], 0, 0, 0);
      }
    }
    __syncthreads();
    cur ^= 1;
  }
  const int r0 = (lane >> 4) * 4, cb = lane & 15;
#pragma unroll
  for (int ni = 0; ni < 4; ni++) {
    const int col = ni * 16 + cb;
    const float sb = scale[col], bb = ebae[col];
    const long row0 = m0 + wave * 16 + r0;
#pragma unroll
    for (int r = 0; r < 4; r++) {
      const long row = row0 + r;
      outa[row * 64 + col] = (acc[ni][r] + bb) * sb * gw[row * 4 + e];
    }
  }
}

// ---------------- combine: out = sum_e a_all[e]
__global__ __launch_bounds__(256) void k_combine(const float* __restrict__ a_all,
                                                 float* __restrict__ out, long n) {
  long i = ((long)blockIdx.x * 256 + threadIdx.x) * 4;
  if (i < n) {
    const float4 v0 = *(const float4*)(a_all + i);
    const float4 v1 = *(const float4*)(a_all + n + i);
    const float4 v2 = *(const float4*)(a_all + 2 * n + i);
    const float4 v3 = *(const float4*)(a_all + 3 * n + i);
    float4 o;
    o.x = v0.x + v1.x + v2.x + v3.x;
    o.y = v0.y + v1.y + v2.y + v3.y;
    o.z = v0.z + v1.z + v2.z + v3.z;
    o.w = v0.w + v1.w + v2.w + v3.w;
    *(float4*)(out + i) = o;
  }
}

// ---------------- launch ----------------
extern "C" void kernel_launch(void* const* d_in, const int* in_sizes, int n_in,
                              void* d_out, int out_size, void* d_ws, size_t ws_size,
                              hipStream_t stream) {
  constexpr int Bn = 16384, S = 512, H0G = 512, H1G = 256, H0E = 1024, H1E = 512, A = 64, E = 4;
  const float* x      = (const float*)d_in[0];
  const float* g_mean = (const float*)d_in[1];
  const float* g_std  = (const float*)d_in[2];
  const float* gW0    = (const float*)d_in[3];
  const float* gb0    = (const float*)d_in[4];
  const float* gW1    = (const float*)d_in[5];
  const float* gb1    = (const float*)d_in[6];
  const float* gWa    = (const float*)d_in[7];
  const float* gba    = (const float*)d_in[8];
  const float* e_mean = (const float*)d_in[9];
  const float* e_std  = (const float*)d_in[10];
  const float* eW0    = (const float*)d_in[11];
  const float* eb0    = (const float*)d_in[12];
  const float* eW1    = (const float*)d_in[13];
  const float* eb1    = (const float*)d_in[14];
  const float* eWa    = (const float*)d_in[15];
  const float* eba    = (const float*)d_in[16];
  const float* scale  = (const float*)d_in[17];
  float* out = (float*)d_out;

  char* p = (char*)d_ws;
  auto alloc = [&](size_t bytes) { char* q = p; p += (bytes + 255) & ~(size_t)255; return q; };
  // common allocations
  f16* xh    = (f16*)alloc((size_t)Bn * S * 2);
  f16* h0g   = (f16*)alloc((size_t)Bn * H0G * 2);
  f16* h1g   = (f16*)alloc((size_t)Bn * H1G * 2);
  float* gw  = (float*)alloc((size_t)Bn * E * 4);
  float* a_all = (float*)alloc((size_t)E * Bn * A * 4);
  f16* gW0t  = (f16*)alloc((size_t)S * H0G * 2);
  f16* gW1t  = (f16*)alloc((size_t)H0G * H1G * 2);
  f16* eW0t  = (f16*)alloc((size_t)E * S * H0E * 2);
  f16* eW1t  = (f16*)alloc((size_t)E * H0E * H1E * 2);
  f16* eWat  = (f16*)alloc((size_t)E * H1E * A * 2);
  float* gb0c = (float*)alloc((size_t)H0G * 4);
  float* eb0c = (float*)alloc((size_t)E * H0E * 4);
  const size_t common = (size_t)(p - (char*)d_ws);
  const size_t merged_extra = (size_t)E * Bn * H0E * 2 + (size_t)E * Bn * H1E * 2 + 512;
  const bool merged = (ws_size >= common + merged_extra);

  // prep
  k_cvt_x<<<2048, 256, 0, stream>>>(x, xh, (long)Bn * S);
  k_transpose<<<dim3(H0G / 32, S / 32, 1), dim3(32, 8), 0, stream>>>(gW0, gW0t, g_std, S, H0G);
  k_transpose<<<dim3(H1G / 32, H0G / 32, 1), dim3(32, 8), 0, stream>>>(gW1, gW1t, nullptr, H0G, H1G);
  k_transpose<<<dim3(H0E / 32, S / 32, E), dim3(32, 8), 0, stream>>>(eW0, eW0t, e_std, S, H0E);
  k_transpose<<<dim3(H1E / 32, H0E / 32, E), dim3(32, 8), 0, stream>>>(eW1, eW1t, nullptr, H0E, H1E);
  k_transpose<<<dim3(A / 32, H1E / 32, E), dim3(32, 8), 0, stream>>>(eWa, eWat, nullptr, H1E, A);
  k_bias_corr<<<dim3(H0G / 64, 1), dim3(64, 16), 0, stream>>>(gW0, gb0, g_mean, g_std, gb0c, S, H0G);
  k_bias_corr<<<dim3(H0E / 64, E), dim3(64, 16), 0, stream>>>(eW0, eb0, e_mean, e_std, eb0c, S, H0E);

  // gating trunk + softmax head
  k_gemm_tanh<<<dim3(H0G / 128, Bn / 128), 256, 0, stream>>>(
      xh, gW0t, gb0c, h0g, Bn, H0G, S, 9, 0, 0, 0, 0);
  k_gemm_tanh<<<dim3(H1G / 128, Bn / 128), 256, 0, stream>>>(
      h0g, gW1t, gb1, h1g, Bn, H1G, H0G, 8, 0, 0, 0, 0);
  k_gating_head<<<Bn / 4, 256, 0, stream>>>(h1g, gWa, gba, gw, Bn);

  if (merged) {
    f16* he0_all = (f16*)alloc((size_t)E * Bn * H0E * 2);  // [E][Bn][1024]
    f16* he1_all = (f16*)alloc((size_t)E * Bn * H1E * 2);  // [E][Bn][512]
    // expert L0, all experts as one N=4096 GEMM (cshift=10 splits C per expert)
    k_gemm_tanh<<<dim3((E * H0E) / 128, Bn / 128), 256, 0, stream>>>(
        xh, eW0t, eb0c, he0_all, Bn, E * H0E, S, 10, 0, 0, 0, 0);
    // expert L1, z-batched
    k_gemm_tanh<<<dim3(H1E / 128, Bn / 128, E), 256, 0, stream>>>(
        he0_all, eW1t, eb1, he1_all, Bn, H1E, H0E, 9,
        (long)Bn * H0E, (long)H0E * H1E, H1E, (long)Bn * H1E);
    // heads, z-batched
    k_head<<<dim3(Bn / 64, 1, E), 256, 0, stream>>>(
        he1_all, eWat, eba, scale, gw, a_all, 0, H1E,
        (long)Bn * H1E, (long)H1E * A, A, (long)Bn * A);
  } else {
    f16* he0 = (f16*)alloc((size_t)Bn * H0E * 2);
    f16* he1 = h0g;  // dead after gating head
    for (int e = 0; e < E; e++) {
      k_gemm_tanh<<<dim3(H0E / 128, Bn / 128), 256, 0, stream>>>(
          xh, eW0t + (size_t)e * S * H0E, eb0c + (size_t)e * H0E, he0, Bn, H0E, S, 10, 0, 0, 0, 0);
      k_gemm_tanh<<<dim3(H1E / 128, Bn / 128), 256, 0, stream>>>(
          he0, eW1t + (size_t)e * H0E * H1E, eb1 + (size_t)e * H1E, he1, Bn, H1E, H0E, 9, 0, 0, 0, 0);
      k_head<<<dim3(Bn / 64, 1, 1), 256, 0, stream>>>(
          he1, eWat + (size_t)e * H1E * A, eba + (size_t)e * A, scale, gw,
          a_all + (size_t)e * Bn * A, e, H1E, 0, 0, 0, 0);
    }
  }
  k_combine<<<(Bn * A) / 1024, 256, 0, stream>>>(a_all, out, (long)Bn * A);
}

// Round 4
// 295.730 us; speedup vs baseline: 2.1572x; 1.3168x over previous
//
#include <hip/hip_runtime.h>
#include <hip/hip_bf16.h>

typedef _Float16 f16;
typedef _Float16 f16x4 __attribute__((ext_vector_type(4)));
typedef _Float16 f16x8 __attribute__((ext_vector_type(8)));
typedef float f32x4 __attribute__((ext_vector_type(4)));

#define DEV static __device__ __forceinline__

DEV void gld_lds16(const void* g, void* l) {
  __builtin_amdgcn_global_load_lds(
      (const __attribute__((address_space(1))) void*)g,
      (__attribute__((address_space(3))) void*)l, 16, 0, 0);
}

DEV float fast_tanh(float x) {
  float e = __expf(2.0f * x);
  return 1.0f - 2.0f / (e + 1.0f);
}

DEV int xcd_swizzle(int raw, int nwg) {
  return ((nwg & 7) == 0) ? ((raw & 7) * (nwg >> 3) + (raw >> 3)) : raw;
}

// ---------------- x (f32) -> xh (f16) ----------------
__global__ __launch_bounds__(256) void k_cvt_x(const float* __restrict__ x,
                                               f16* __restrict__ xh, long n) {
  long i0 = ((long)blockIdx.x * 256 + threadIdx.x) * 4;
  long stride = (long)gridDim.x * 1024;
  for (long i = i0; i < n; i += stride) {
    const float4 v = *(const float4*)(x + i);
    f16x4 h;
    h.x = (f16)v.x; h.y = (f16)v.y; h.z = (f16)v.z; h.w = (f16)v.w;
    *(f16x4*)(xh + i) = h;
  }
}

// ---------------- W [E][K][N] f32 -> Wt [E][N][K] f16, optional col-scale 1/std[k]
__global__ __launch_bounds__(256) void k_transpose(const float* __restrict__ in,
                                                   f16* __restrict__ out,
                                                   const float* __restrict__ stdv,
                                                   int K_, int N_) {
  __shared__ float tile[32][33];
  const int e = blockIdx.z;
  const float* ine = in + (long)e * K_ * N_;
  f16* oute = out + (long)e * K_ * N_;
  const int n0 = blockIdx.x * 32, k0 = blockIdx.y * 32;
  const int tx = threadIdx.x, ty = threadIdx.y;
#pragma unroll
  for (int j = 0; j < 4; j++)
    tile[ty + j * 8][tx] = ine[(long)(k0 + ty + j * 8) * N_ + n0 + tx];
  __syncthreads();
  const float rs = stdv ? 1.0f / stdv[(long)e * K_ + k0 + tx] : 1.0f;
#pragma unroll
  for (int j = 0; j < 4; j++)
    oute[(long)(n0 + ty + j * 8) * K_ + k0 + tx] = (f16)(tile[tx][ty + j * 8] * rs);
}

// ---------------- corrected bias: outb[e][h] = b[e][h] - sum_s (mean/std)[e][s]*W[e][s][h]
__global__ __launch_bounds__(1024) void k_bias_corr(const float* __restrict__ W,
                                                    const float* __restrict__ b,
                                                    const float* __restrict__ mean,
                                                    const float* __restrict__ stdv,
                                                    float* __restrict__ outb,
                                                    int S_, int H_) {
  __shared__ float red[16][64];
  const int e = blockIdx.y;
  const float* We = W + (long)e * S_ * H_;
  const float* me = mean + (long)e * S_;
  const float* se = stdv + (long)e * S_;
  const int h = blockIdx.x * 64 + threadIdx.x;
  const int sl = threadIdx.y;
  float acc = 0.0f;
#pragma unroll 4
  for (int s = sl; s < S_; s += 16) acc += (me[s] / se[s]) * We[(long)s * H_ + h];
  red[sl][threadIdx.x] = acc;
  __syncthreads();
  if (sl == 0) {
    float a = 0.0f;
#pragma unroll
    for (int j = 0; j < 16; j++) a += red[j][threadIdx.x];
    outb[(long)e * H_ + h] = b[(long)e * H_ + h] - a;
  }
}

// ---------------- main GEMM: C = tanh(A @ Bt^T + bias), dbuf, XOR-swizzled LDS
// LDS tile [128][64] f16 (128B rows): global source chunk pre-swizzled by
// (row&7) so ds_read fragment reads spread across banks (2-way, free).
__global__ __launch_bounds__(256) void k_gemm_tanh(
    const f16* __restrict__ A, const f16* __restrict__ Bt,
    const float* __restrict__ bias, f16* __restrict__ C,
    int M, int N, int K,
    long sA, long sB, long sBias, long sC) {
  A += (long)blockIdx.z * sA; Bt += (long)blockIdx.z * sB;
  bias += (long)blockIdx.z * sBias; C += (long)blockIdx.z * sC;
  __shared__ __align__(16) f16 As[2][128 * 64];
  __shared__ __align__(16) f16 Bs[2][128 * 64];
  const int tid = threadIdx.x, wave = tid >> 6, lane = tid & 63;
  const int nwg = gridDim.x * gridDim.y;
  const int logical = xcd_swizzle(blockIdx.y * gridDim.x + blockIdx.x, nwg);
  const int bx = logical % gridDim.x, by = logical / gridDim.x;
  const int m0 = by * 128, n0 = bx * 128;
  const int wr = wave >> 1, wc = wave & 1;
  f32x4 acc[4][4] = {};
  // pre-swizzled global chunk: chunk ^= (row&7); row&7 == (tid/8)&7 for staging
  const int swz_chunk = (tid & 7) ^ ((tid >> 3) & 7);
  const f16* Ag = A + (long)(m0 + tid / 8) * K + swz_chunk * 8;
  const f16* Bg = Bt + (long)(n0 + tid / 8) * K + swz_chunk * 8;
  const int wo = wave * 512;

#pragma unroll
  for (int i = 0; i < 4; i++) {
    gld_lds16(Ag + (long)i * 32 * K, &As[0][wo + i * 2048]);
    gld_lds16(Bg + (long)i * 32 * K, &Bs[0][wo + i * 2048]);
  }
  __syncthreads();

  const int nt = K >> 6;
  int cur = 0;
  for (int t = 0; t < nt; ++t) {
    if (t + 1 < nt) {
      const long kt = (long)(t + 1) << 6;
#pragma unroll
      for (int i = 0; i < 4; i++) {
        gld_lds16(Ag + (long)i * 32 * K + kt, &As[cur ^ 1][wo + i * 2048]);
        gld_lds16(Bg + (long)i * 32 * K + kt, &Bs[cur ^ 1][wo + i * 2048]);
      }
    }
#pragma unroll
    for (int kk = 0; kk < 2; kk++) {
      f16x8 af[4], bfr[4];
      const int rchunk = (kk * 4 + (lane >> 4)) ^ (lane & 7);  // read-side XOR
#pragma unroll
      for (int mi = 0; mi < 4; mi++)
        af[mi] = *(const f16x8*)&As[cur][(wr * 64 + mi * 16 + (lane & 15)) * 64 + rchunk * 8];
#pragma unroll
      for (int ni = 0; ni < 4; ni++)
        bfr[ni] = *(const f16x8*)&Bs[cur][(wc * 64 + ni * 16 + (lane & 15)) * 64 + rchunk * 8];
#pragma unroll
      for (int mi = 0; mi < 4; mi++)
#pragma unroll
        for (int ni = 0; ni < 4; ni++)
          acc[mi][ni] = __builtin_amdgcn_mfma_f32_16x16x32_f16(af[mi], bfr[ni], acc[mi][ni], 0, 0, 0);
    }
    __syncthreads();
    cur ^= 1;
  }

  const int r0 = (lane >> 4) * 4, cb = lane & 15;
#pragma unroll
  for (int ni = 0; ni < 4; ni++) {
    const int col = n0 + wc * 64 + ni * 16 + cb;
    const float bc = bias[col];
#pragma unroll
    for (int mi = 0; mi < 4; mi++) {
      const int row = m0 + wr * 64 + mi * 16 + r0;
#pragma unroll
      for (int r = 0; r < 4; r++)
        C[(long)(row + r) * N + col] = (f16)fast_tanh(acc[mi][ni][r] + bc);
    }
  }
}

// ---------------- gating head: logits = h1 @ gWa + gba; softmax over 4 -> gw [B,4] f32
__global__ __launch_bounds__(256) void k_gating_head(const f16* __restrict__ h1,
                                                     const float* __restrict__ gWa,
                                                     const float* __restrict__ gba,
                                                     float* __restrict__ gw, int B_) {
  const int b = blockIdx.x * 4 + (threadIdx.x >> 6);
  const int lane = threadIdx.x & 63;
  const f16x4 hv = *(const f16x4*)&h1[(long)b * 256 + lane * 4];
  float s0 = 0, s1 = 0, s2 = 0, s3 = 0;
#pragma unroll
  for (int j = 0; j < 4; j++) {
    const float hh = (float)hv[j];
    const float4 wr4 = *(const float4*)&gWa[(lane * 4 + j) * 4];
    s0 += hh * wr4.x; s1 += hh * wr4.y; s2 += hh * wr4.z; s3 += hh * wr4.w;
  }
#pragma unroll
  for (int off = 32; off >= 1; off >>= 1) {
    s0 += __shfl_xor(s0, off);
    s1 += __shfl_xor(s1, off);
    s2 += __shfl_xor(s2, off);
    s3 += __shfl_xor(s3, off);
  }
  const float l0 = s0 + gba[0], l1 = s1 + gba[1], l2 = s2 + gba[2], l3 = s3 + gba[3];
  float mx = fmaxf(fmaxf(l0, l1), fmaxf(l2, l3));
  const float e0 = __expf(l0 - mx), e1 = __expf(l1 - mx), e2 = __expf(l2 - mx), e3 = __expf(l3 - mx);
  const float inv = 1.0f / (e0 + e1 + e2 + e3);
  if (lane == 0) {
    float4 o; o.x = e0 * inv; o.y = e1 * inv; o.z = e2 * inv; o.w = e3 * inv;
    *(float4*)&gw[(long)b * 4] = o;
  }
}

// ---------------- expert head: a_all[e][b][a] = gw[b,e] * ((he1 @ Wt^T)[b,a] + eba[a]) * scale[a]
__global__ __launch_bounds__(256) void k_head(const f16* __restrict__ he1,
                                              const f16* __restrict__ Wt,
                                              const float* __restrict__ ebae,
                                              const float* __restrict__ scale,
                                              const float* __restrict__ gw,
                                              float* __restrict__ outa,
                                              int e0, int K,
                                              long sA, long sB, long sBias, long sC) {
  const int z = blockIdx.z;
  he1 += (long)z * sA; Wt += (long)z * sB; ebae += (long)z * sBias; outa += (long)z * sC;
  const int e = e0 + z;
  __shared__ __align__(16) f16 As[2][64 * 64];
  __shared__ __align__(16) f16 Bs[2][64 * 64];
  const int tid = threadIdx.x, wave = tid >> 6, lane = tid & 63;
  const int bid = xcd_swizzle(blockIdx.x, gridDim.x);
  const long m0 = (long)bid * 64;
  f32x4 acc[4] = {};
  const int swz_chunk = (tid & 7) ^ ((tid >> 3) & 7);
  const f16* Ag = he1 + (m0 + tid / 8) * K + swz_chunk * 8;
  const f16* Bg = Wt + (long)(tid / 8) * K + swz_chunk * 8;
  const int wo = wave * 512;
#pragma unroll
  for (int i = 0; i < 2; i++) {
    gld_lds16(Ag + (long)i * 32 * K, &As[0][wo + i * 2048]);
    gld_lds16(Bg + (long)i * 32 * K, &Bs[0][wo + i * 2048]);
  }
  __syncthreads();
  const int nt = K >> 6;
  int cur = 0;
  for (int t = 0; t < nt; ++t) {
    if (t + 1 < nt) {
      const long kt = (long)(t + 1) << 6;
#pragma unroll
      for (int i = 0; i < 2; i++) {
        gld_lds16(Ag + (long)i * 32 * K + kt, &As[cur ^ 1][wo + i * 2048]);
        gld_lds16(Bg + (long)i * 32 * K + kt, &Bs[cur ^ 1][wo + i * 2048]);
      }
    }
#pragma unroll
    for (int kk = 0; kk < 2; kk++) {
      const int rchunk = (kk * 4 + (lane >> 4)) ^ (lane & 7);
      const f16x8 a = *(const f16x8*)&As[cur][(wave * 16 + (lane & 15)) * 64 + rchunk * 8];
#pragma unroll
      for (int ni = 0; ni < 4; ni++) {
        const f16x8 bq = *(const f16x8*)&Bs[cur][(ni * 16 + (lane & 15)) * 64 + rchunk * 8];
        acc[ni] = __builtin_amdgcn_mfma_f32_16x16x32_f16(a, bq, acc[ni], 0, 0, 0);
      }
    }
    __syncthreads();
    cur ^= 1;
  }
  const int r0 = (lane >> 4) * 4, cb = lane & 15;
#pragma unroll
  for (int ni = 0; ni < 4; ni++) {
    const int col = ni * 16 + cb;
    const float sb = scale[col], bb = ebae[col];
    const long row0 = m0 + wave * 16 + r0;
#pragma unroll
    for (int r = 0; r < 4; r++) {
      const long row = row0 + r;
      outa[row * 64 + col] = (acc[ni][r] + bb) * sb * gw[row * 4 + e];
    }
  }
}

// ---------------- combine: out = sum_e a_all[e]
__global__ __launch_bounds__(256) void k_combine(const float* __restrict__ a_all,
                                                 float* __restrict__ out, long n) {
  long i = ((long)blockIdx.x * 256 + threadIdx.x) * 4;
  if (i < n) {
    const float4 v0 = *(const float4*)(a_all + i);
    const float4 v1 = *(const float4*)(a_all + n + i);
    const float4 v2 = *(const float4*)(a_all + 2 * n + i);
    const float4 v3 = *(const float4*)(a_all + 3 * n + i);
    float4 o;
    o.x = v0.x + v1.x + v2.x + v3.x;
    o.y = v0.y + v1.y + v2.y + v3.y;
    o.z = v0.z + v1.z + v2.z + v3.z;
    o.w = v0.w + v1.w + v2.w + v3.w;
    *(float4*)(out + i) = o;
  }
}

// ---------------- launch ----------------
extern "C" void kernel_launch(void* const* d_in, const int* in_sizes, int n_in,
                              void* d_out, int out_size, void* d_ws, size_t ws_size,
                              hipStream_t stream) {
  constexpr int Bn = 16384, S = 512, H0G = 512, H1G = 256, H0E = 1024, H1E = 512, A = 64, E = 4;
  const float* x      = (const float*)d_in[0];
  const float* g_mean = (const float*)d_in[1];
  const float* g_std  = (const float*)d_in[2];
  const float* gW0    = (const float*)d_in[3];
  const float* gb0    = (const float*)d_in[4];
  const float* gW1    = (const float*)d_in[5];
  const float* gb1    = (const float*)d_in[6];
  const float* gWa    = (const float*)d_in[7];
  const float* gba    = (const float*)d_in[8];
  const float* e_mean = (const float*)d_in[9];
  const float* e_std  = (const float*)d_in[10];
  const float* eW0    = (const float*)d_in[11];
  const float* eb0    = (const float*)d_in[12];
  const float* eW1    = (const float*)d_in[13];
  const float* eb1    = (const float*)d_in[14];
  const float* eWa    = (const float*)d_in[15];
  const float* eba    = (const float*)d_in[16];
  const float* scale  = (const float*)d_in[17];
  float* out = (float*)d_out;

  char* p = (char*)d_ws;
  auto alloc = [&](size_t bytes) { char* q = p; p += (bytes + 255) & ~(size_t)255; return q; };
  f16* xh    = (f16*)alloc((size_t)Bn * S * 2);
  float* gw  = (float*)alloc((size_t)Bn * E * 4);
  float* a_all = (float*)alloc((size_t)E * Bn * A * 4);
  f16* gW0t  = (f16*)alloc((size_t)S * H0G * 2);
  f16* gW1t  = (f16*)alloc((size_t)H0G * H1G * 2);
  f16* eW0t  = (f16*)alloc((size_t)E * S * H0E * 2);
  f16* eW1t  = (f16*)alloc((size_t)E * H0E * H1E * 2);
  f16* eWat  = (f16*)alloc((size_t)E * H1E * A * 2);
  float* gb0c = (float*)alloc((size_t)H0G * 4);
  float* eb0c = (float*)alloc((size_t)E * H0E * 4);
  const size_t base = (size_t)(p - (char*)d_ws);
  // pick largest expert-group g in {4,2,1} fitting ws: needs g*(he0+he1)
  const size_t per_g = ((size_t)Bn * H0E * 2 + 256) + ((size_t)Bn * H1E * 2 + 256);
  int g = 1;
  if (ws_size >= base + 4 * per_g) g = 4;
  else if (ws_size >= base + 2 * per_g) g = 2;
  f16* he0_g = (f16*)alloc((size_t)g * Bn * H0E * 2);
  f16* he1_g = (f16*)alloc((size_t)g * Bn * H1E * 2);
  // gating scratch aliases expert scratch (he0_g written only after gating done)
  f16* h0g = he0_g;                    // needs 16 MB, he0_g >= 32 MB
  f16* h1g = he1_g;                    // needs 8 MB, he1_g >= 16 MB

  // prep
  k_cvt_x<<<2048, 256, 0, stream>>>(x, xh, (long)Bn * S);
  k_transpose<<<dim3(H0G / 32, S / 32, 1), dim3(32, 8), 0, stream>>>(gW0, gW0t, g_std, S, H0G);
  k_transpose<<<dim3(H1G / 32, H0G / 32, 1), dim3(32, 8), 0, stream>>>(gW1, gW1t, nullptr, H0G, H1G);
  k_transpose<<<dim3(H0E / 32, S / 32, E), dim3(32, 8), 0, stream>>>(eW0, eW0t, e_std, S, H0E);
  k_transpose<<<dim3(H1E / 32, H0E / 32, E), dim3(32, 8), 0, stream>>>(eW1, eW1t, nullptr, H0E, H1E);
  k_transpose<<<dim3(A / 32, H1E / 32, E), dim3(32, 8), 0, stream>>>(eWa, eWat, nullptr, H1E, A);
  k_bias_corr<<<dim3(H0G / 64, 1), dim3(64, 16), 0, stream>>>(gW0, gb0, g_mean, g_std, gb0c, S, H0G);
  k_bias_corr<<<dim3(H0E / 64, E), dim3(64, 16), 0, stream>>>(eW0, eb0, e_mean, e_std, eb0c, S, H0E);

  // gating trunk + softmax head
  k_gemm_tanh<<<dim3(H0G / 128, Bn / 128), 256, 0, stream>>>(
      xh, gW0t, gb0c, h0g, Bn, H0G, S, 0, 0, 0, 0);
  k_gemm_tanh<<<dim3(H1G / 128, Bn / 128), 256, 0, stream>>>(
      h0g, gW1t, gb1, h1g, Bn, H1G, H0G, 0, 0, 0, 0);
  k_gating_head<<<Bn / 4, 256, 0, stream>>>(h1g, gWa, gba, gw, Bn);

  // experts in groups of g, z-batched
  for (int e0 = 0; e0 < E; e0 += g) {
    k_gemm_tanh<<<dim3(H0E / 128, Bn / 128, g), 256, 0, stream>>>(
        xh, eW0t + (size_t)e0 * S * H0E, eb0c + (size_t)e0 * H0E, he0_g,
        Bn, H0E, S, 0, (long)S * H0E, H0E, (long)Bn * H0E);
    k_gemm_tanh<<<dim3(H1E / 128, Bn / 128, g), 256, 0, stream>>>(
        he0_g, eW1t + (size_t)e0 * H0E * H1E, eb1 + (size_t)e0 * H1E, he1_g,
        Bn, H1E, H0E, (long)Bn * H0E, (long)H0E * H1E, H1E, (long)Bn * H1E);
    k_head<<<dim3(Bn / 64, 1, g), 256, 0, stream>>>(
        he1_g, eWat + (size_t)e0 * H1E * A, eba + (size_t)e0 * A, scale, gw,
        a_all + (size_t)e0 * Bn * A, e0, H1E,
        (long)Bn * H1E, (long)H1E * A, A, (long)Bn * A);
  }
  k_combine<<<(Bn * A) / 1024, 256, 0, stream>>>(a_all, out, (long)Bn * A);
}